// Round 4
// baseline (645.751 us; speedup 1.0000x reference)
//
#include <hip/hip_runtime.h>
#include <hip/hip_bf16.h>

// Problem constants
#define B_   4
#define N_   4096
#define IND  512
#define ATT  64
#define QKD  128   // 2*ATT

// adj@k split-K
#define KSPLIT 4
#define KCHUNK 1024   // 4096 / KSPLIT

typedef __attribute__((ext_vector_type(8))) short short8v;  // 8 bf16
typedef __attribute__((ext_vector_type(4))) float f32x4;

// ---------------------------------------------------------------------------
// GEMM NT: C[M][Nout] = X[M][K] @ W[Nout][K]^T   (all f32, row-major)
// 64x64 tile, K-tile 32, 256 threads, 4x4 micro-tile per thread.
// ---------------------------------------------------------------------------
__global__ __launch_bounds__(256)
void gemm_nt_f32(const float* __restrict__ X, const float* __restrict__ W,
                 float* __restrict__ C, int M, int K, int Nout) {
  __shared__ __align__(16) float Xs[32][68];
  __shared__ __align__(16) float Ws[32][68];
  const int tid = threadIdx.x;
  const int tx = tid & 15, ty = tid >> 4;
  const int m0 = blockIdx.x * 64, n0 = blockIdx.y * 64;

  float acc[4][4] = {};

  for (int k0 = 0; k0 < K; k0 += 32) {
    for (int f = tid; f < 512; f += 256) {
      const int r = f >> 3;              // 0..63
      const int c4 = (f & 7) << 2;       // 0,4,...,28
      const float4 vx = *(const float4*)(X + (size_t)(m0 + r) * K + k0 + c4);
      Xs[c4 + 0][r] = vx.x; Xs[c4 + 1][r] = vx.y;
      Xs[c4 + 2][r] = vx.z; Xs[c4 + 3][r] = vx.w;
      const float4 vw = *(const float4*)(W + (size_t)(n0 + r) * K + k0 + c4);
      Ws[c4 + 0][r] = vw.x; Ws[c4 + 1][r] = vw.y;
      Ws[c4 + 2][r] = vw.z; Ws[c4 + 3][r] = vw.w;
    }
    __syncthreads();

#pragma unroll
    for (int kk = 0; kk < 32; ++kk) {
      const float4 a = *(const float4*)&Xs[kk][ty << 2];
      const float4 b = *(const float4*)&Ws[kk][tx << 2];
      const float av[4] = {a.x, a.y, a.z, a.w};
      const float bv[4] = {b.x, b.y, b.z, b.w};
#pragma unroll
      for (int i = 0; i < 4; ++i)
#pragma unroll
        for (int j = 0; j < 4; ++j) acc[i][j] += av[i] * bv[j];
    }
    __syncthreads();
  }

#pragma unroll
  for (int i = 0; i < 4; ++i) {
    float4 o = make_float4(acc[i][0], acc[i][1], acc[i][2], acc[i][3]);
    *(float4*)(C + (size_t)(m0 + (ty << 2) + i) * Nout + n0 + (tx << 2)) = o;
  }
}

// ---------------------------------------------------------------------------
// prep_k: k part of qk (f32, strided) -> kt_hi/kt_lo[b][ch][m] (bf16 bits,
// transposed so adjk's B-frags are contiguous along m).
// hi = truncate-to-bf16(v), lo = truncate-to-bf16(v - hi): combined rel err
// ~2^-16, preserving the exp-sensitive wpre path.
// One block per (b, 64-m tile); LDS-tiled transpose, coalesced both sides.
// ---------------------------------------------------------------------------
__global__ __launch_bounds__(256)
void prep_k(const float* __restrict__ qk, unsigned short* __restrict__ kt_hi,
            unsigned short* __restrict__ kt_lo) {
  __shared__ unsigned short sh[64][66];
  __shared__ unsigned short sl[64][66];
  const int b  = blockIdx.x >> 6;
  const int m0 = (blockIdx.x & 63) * 64;
  const int t = threadIdx.x;

#pragma unroll
  for (int i = 0; i < 16; ++i) {
    const int f = t + i * 256;
    const int ml = f >> 6, ch = f & 63;     // consecutive t -> consecutive ch
    const float v = qk[((size_t)b * N_ + m0 + ml) * QKD + ATT + ch];
    const unsigned short hi = (unsigned short)(__float_as_uint(v) >> 16);
    const float fhi = __uint_as_float((unsigned)hi << 16);
    const unsigned short lo = (unsigned short)(__float_as_uint(v - fhi) >> 16);
    sh[ch][ml] = hi;
    sl[ch][ml] = lo;
  }
  __syncthreads();
#pragma unroll
  for (int i = 0; i < 16; ++i) {
    const int f = t + i * 256;
    const int ch = f >> 6, ml = f & 63;     // consecutive t -> consecutive m
    kt_hi[((size_t)b * ATT + ch) * N_ + m0 + ml] = sh[ch][ml];
    kt_lo[((size_t)b * ATT + ch) * N_ + m0 + ml] = sl[ch][ml];
  }
}

// ---------------------------------------------------------------------------
// ka_partial = adj @ (k_hi + k_lo) via bf16 MFMA, no LDS, no barriers.
// Each wave owns 16 output rows x all 64 channels (4 col-tiles of 16x16),
// streams its adj rows from HBM (A-frag loads merge to 128B lines in L1/L2),
// gathers B-frags from L2-resident kt. adj in {0,1} is exact in bf16.
// A-frag (16x16x32): lane l -> row l&15, k = (l>>4)*8 + j (contiguous).
// B-frag: lane l -> col l&15, k = (l>>4)*8 + j (contiguous along m in kt).
// C/D: col = l&15, row = (l>>4)*4 + reg   [m89-verified layout].
// ---------------------------------------------------------------------------
__global__ __launch_bounds__(256)
void adjk_mfma(const float* __restrict__ adj,
               const unsigned short* __restrict__ kt_hi,
               const unsigned short* __restrict__ kt_lo,
               float* __restrict__ kapart) {
  const int lane = threadIdx.x & 63;
  const int wid  = threadIdx.x >> 6;
  const int g0   = blockIdx.x * 64 + wid * 16;  // global output row tile
  const int b    = g0 >> 12;                    // batch
  const int split = blockIdx.y;
  const int k0   = split * KCHUNK;

  const int arow = lane & 15;
  const int koff = (lane >> 4) * 8;

  const float* aptr = adj + (size_t)(g0 + arow) * N_ + k0 + koff;
  const unsigned short* hbase = kt_hi + ((size_t)b * ATT + (lane & 15)) * N_ + k0 + koff;
  const unsigned short* lbase = kt_lo + ((size_t)b * ATT + (lane & 15)) * N_ + k0 + koff;

  f32x4 acc[4] = {{0.f,0.f,0.f,0.f},{0.f,0.f,0.f,0.f},
                  {0.f,0.f,0.f,0.f},{0.f,0.f,0.f,0.f}};

#pragma unroll 2
  for (int ks = 0; ks < KCHUNK; ks += 32) {
    // A-frag: 8 adj f32 -> bf16 by bit-truncation (exact for 0.0 / 1.0)
    const float4 a0 = *(const float4*)(aptr + ks);
    const float4 a1 = *(const float4*)(aptr + ks + 4);
    union { short8v v; unsigned short u[8]; } af;
    const float av[8] = {a0.x, a0.y, a0.z, a0.w, a1.x, a1.y, a1.z, a1.w};
#pragma unroll
    for (int j = 0; j < 8; ++j)
      af.u[j] = (unsigned short)(__float_as_uint(av[j]) >> 16);

#pragma unroll
    for (int c = 0; c < 4; ++c) {
      const short8v bh = *(const short8v*)(hbase + (size_t)c * 16 * N_ + ks);
      const short8v bl = *(const short8v*)(lbase + (size_t)c * 16 * N_ + ks);
      acc[c] = __builtin_amdgcn_mfma_f32_16x16x32_bf16(af.v, bh, acc[c], 0, 0, 0);
      acc[c] = __builtin_amdgcn_mfma_f32_16x16x32_bf16(af.v, bl, acc[c], 0, 0, 0);
    }
  }

  // write partials: kapart[split][g][ch]
  float* outp = kapart + ((size_t)split * (B_ * N_) + g0 + (lane >> 4) * 4) * ATT + (lane & 15);
#pragma unroll
  for (int c = 0; c < 4; ++c)
#pragma unroll
    for (int r = 0; r < 4; ++r)
      outp[(size_t)r * ATT + c * 16] = acc[c][r];
}

// ---------------------------------------------------------------------------
// wpre[row] = (1/8) * q[row] . (sum of KSPLIT ka partials)  — one wave/row
// ---------------------------------------------------------------------------
__global__ __launch_bounds__(256)
void qdot(const float* __restrict__ qk, const float* __restrict__ kapart,
          float* __restrict__ wpre) {
  const int wid  = threadIdx.x >> 6;
  const int lane = threadIdx.x & 63;
  const int row  = blockIdx.x * 4 + wid;   // b*N + n

  float ka = 0.f;
#pragma unroll
  for (int s = 0; s < KSPLIT; ++s)
    ka += kapart[((size_t)s * B_ * N_ + row) * ATT + lane];

  const float q = qk[(size_t)row * QKD + lane];
  float val = q * ka;
#pragma unroll
  for (int off = 32; off; off >>= 1) val += __shfl_xor(val, off);
  if (lane == 0) wpre[row] = val * 0.125f;   // 1/sqrt(64)
}

// ---------------------------------------------------------------------------
// Softmax over the bag dimension (N=4096) per batch, in-place.
// ---------------------------------------------------------------------------
__global__ __launch_bounds__(256)
void softmax_bag(float* __restrict__ w) {
  __shared__ float red[256];
  const int b = blockIdx.x;
  float* wb = w + (size_t)b * N_;
  const int t = threadIdx.x;

  float vals[16];
  float mx = -1e30f;
#pragma unroll
  for (int i = 0; i < 16; ++i) {
    vals[i] = wb[t + i * 256];
    mx = fmaxf(mx, vals[i]);
  }
  red[t] = mx; __syncthreads();
  for (int s = 128; s; s >>= 1) {
    if (t < s) red[t] = fmaxf(red[t], red[t + s]);
    __syncthreads();
  }
  mx = red[0];
  __syncthreads();

  float sum = 0.f;
#pragma unroll
  for (int i = 0; i < 16; ++i) {
    vals[i] = expf(vals[i] - mx);
    sum += vals[i];
  }
  red[t] = sum; __syncthreads();
  for (int s = 128; s; s >>= 1) {
    if (t < s) red[t] += red[t + s];
    __syncthreads();
  }
  const float inv = 1.f / red[0];
#pragma unroll
  for (int i = 0; i < 16; ++i) wb[t + i * 256] = vals[i] * inv;
}

// ---------------------------------------------------------------------------
// out[b,n,:] *= w[b,n]   (v was written directly into d_out)
// ---------------------------------------------------------------------------
__global__ __launch_bounds__(256)
void scale_v(float* __restrict__ out, const float* __restrict__ w, int total4) {
  int idx = blockIdx.x * blockDim.x + threadIdx.x;
  const int stride = gridDim.x * blockDim.x;
  for (; idx < total4; idx += stride) {
    float4 v = ((const float4*)out)[idx];
    const float s = w[idx >> 7];                  // 512/4 = 128 float4 per row
    v.x *= s; v.y *= s; v.z *= s; v.w *= s;
    ((float4*)out)[idx] = v;
  }
}

extern "C" void kernel_launch(void* const* d_in, const int* in_sizes, int n_in,
                              void* d_out, int out_size, void* d_ws, size_t ws_size,
                              hipStream_t stream) {
  const float* x    = (const float*)d_in[0];   // (B,N,512)
  const float* adj  = (const float*)d_in[1];   // (B,N,N)
  const float* W_qk = (const float*)d_in[2];   // (128,512)
  const float* W_v  = (const float*)d_in[3];   // (512,512)
  float* out = (float*)d_out;                  // (B,N,512)

  float* qk     = (float*)d_ws;                              // 8 MB
  float* kapart = qk + (size_t)B_ * N_ * QKD;                // 16 MB
  float* wpre   = kapart + (size_t)KSPLIT * B_ * N_ * ATT;   // 64 KB
  unsigned short* kt_hi = (unsigned short*)(wpre + B_ * N_); // 2 MB
  unsigned short* kt_lo = kt_hi + (size_t)B_ * ATT * N_;     // 2 MB

  const int M = B_ * N_;  // 16384

  // v = x @ W_v^T  -> directly into d_out
  {
    dim3 grid(M / 64, IND / 64);
    gemm_nt_f32<<<grid, 256, 0, stream>>>(x, W_v, out, M, IND, IND);
  }
  // qk = x @ W_qk^T -> workspace
  {
    dim3 grid(M / 64, QKD / 64);
    gemm_nt_f32<<<grid, 256, 0, stream>>>(x, W_qk, qk, M, IND, QKD);
  }
  // k -> transposed bf16 hi/lo
  prep_k<<<B_ * 64, 256, 0, stream>>>(qk, kt_hi, kt_lo);
  // ka partials = adj @ k via streaming bf16 MFMA
  {
    dim3 grid(M / 64, KSPLIT);
    adjk_mfma<<<grid, 256, 0, stream>>>(adj, kt_hi, kt_lo, kapart);
  }
  // wpre = q . ka / 8
  qdot<<<M / 4, 256, 0, stream>>>(qk, kapart, wpre);
  // softmax over bag dim
  softmax_bag<<<B_, 256, 0, stream>>>(wpre);
  // out *= w
  const int total4 = M * (IND / 4);
  scale_v<<<2048, 256, 0, stream>>>(out, wpre, total4);
}

// Round 5
// 603.769 us; speedup vs baseline: 1.0695x; 1.0695x over previous
//
#include <hip/hip_runtime.h>
#include <hip/hip_bf16.h>

// Problem constants
#define B_   4
#define N_   4096
#define IND  512
#define ATT  64
#define QKD  128   // 2*ATT

// adj@k split-K
#define KSPLIT 4
#define KCHUNK 1024   // 4096 / KSPLIT; 32 slabs of 32 k's each

typedef __attribute__((ext_vector_type(8))) short short8v;  // 8 bf16
typedef __attribute__((ext_vector_type(4))) float f32x4;

// ---------------------------------------------------------------------------
// GEMM NT: C[M][Nout] = X[M][K] @ W[Nout][K]^T   (all f32, row-major)
// 64x64 tile, K-tile 32, 256 threads, 4x4 micro-tile per thread.
// ---------------------------------------------------------------------------
__global__ __launch_bounds__(256)
void gemm_nt_f32(const float* __restrict__ X, const float* __restrict__ W,
                 float* __restrict__ C, int M, int K, int Nout) {
  __shared__ __align__(16) float Xs[32][68];
  __shared__ __align__(16) float Ws[32][68];
  const int tid = threadIdx.x;
  const int tx = tid & 15, ty = tid >> 4;
  const int m0 = blockIdx.x * 64, n0 = blockIdx.y * 64;

  float acc[4][4] = {};

  for (int k0 = 0; k0 < K; k0 += 32) {
    for (int f = tid; f < 512; f += 256) {
      const int r = f >> 3;              // 0..63
      const int c4 = (f & 7) << 2;       // 0,4,...,28
      const float4 vx = *(const float4*)(X + (size_t)(m0 + r) * K + k0 + c4);
      Xs[c4 + 0][r] = vx.x; Xs[c4 + 1][r] = vx.y;
      Xs[c4 + 2][r] = vx.z; Xs[c4 + 3][r] = vx.w;
      const float4 vw = *(const float4*)(W + (size_t)(n0 + r) * K + k0 + c4);
      Ws[c4 + 0][r] = vw.x; Ws[c4 + 1][r] = vw.y;
      Ws[c4 + 2][r] = vw.z; Ws[c4 + 3][r] = vw.w;
    }
    __syncthreads();

#pragma unroll
    for (int kk = 0; kk < 32; ++kk) {
      const float4 a = *(const float4*)&Xs[kk][ty << 2];
      const float4 b = *(const float4*)&Ws[kk][tx << 2];
      const float av[4] = {a.x, a.y, a.z, a.w};
      const float bv[4] = {b.x, b.y, b.z, b.w};
#pragma unroll
      for (int i = 0; i < 4; ++i)
#pragma unroll
        for (int j = 0; j < 4; ++j) acc[i][j] += av[i] * bv[j];
    }
    __syncthreads();
  }

#pragma unroll
  for (int i = 0; i < 4; ++i) {
    float4 o = make_float4(acc[i][0], acc[i][1], acc[i][2], acc[i][3]);
    *(float4*)(C + (size_t)(m0 + (ty << 2) + i) * Nout + n0 + (tx << 2)) = o;
  }
}

// ---------------------------------------------------------------------------
// prep_k: k part of qk (f32) -> frag-linear bf16 hi/lo table:
//   ktf[((((b*128 + slab)*4 + c)*2 + h)*64 + lane)*8 + j]
//     = bf16_h( k[b][ m = slab*32 + (lane>>4)*8 + j ][ ch = c*16 + (lane&15) ] )
// so adjk's B-frag loads are single fully-coalesced 16B/lane (1KB/wave).
// hi = truncate-to-bf16(v), lo = truncate-to-bf16(v - hi) (rel err ~2^-16).
// One block per (b, slab of 32 m's).
// ---------------------------------------------------------------------------
__global__ __launch_bounds__(256)
void prep_k(const float* __restrict__ qk, unsigned short* __restrict__ ktf) {
  __shared__ unsigned short sh[32][68];
  __shared__ unsigned short sl[32][68];
  const int b    = blockIdx.x >> 7;
  const int slab = blockIdx.x & 127;
  const int t = threadIdx.x;

#pragma unroll
  for (int i = 0; i < 2; ++i) {
    const int f = t + i * 256;          // 0..511 float4s
    const int ml  = f >> 4;             // 0..31
    const int ch4 = (f & 15) << 2;      // 0..60
    const float4 v = *(const float4*)(qk +
        ((size_t)b * N_ + slab * 32 + ml) * QKD + ATT + ch4);
    const float vv[4] = {v.x, v.y, v.z, v.w};
#pragma unroll
    for (int j = 0; j < 4; ++j) {
      const unsigned short hi = (unsigned short)(__float_as_uint(vv[j]) >> 16);
      const float fhi = __uint_as_float((unsigned)hi << 16);
      const unsigned short lo = (unsigned short)(__float_as_uint(vv[j] - fhi) >> 16);
      sh[ml][ch4 + j] = hi;
      sl[ml][ch4 + j] = lo;
    }
  }
  __syncthreads();

  const int lane = t & 63;
  const int c    = t >> 6;              // 0..3
  const int mb   = (lane >> 4) << 3;    // m base: 0,8,16,24
  const int ch   = c * 16 + (lane & 15);
  unsigned short* outb = ktf +
      (((size_t)(b * 128 + slab) * 4 + c) * 2) * 512 + (size_t)lane * 8;
  union { short8v v; unsigned short u[8]; } hv, lv;
#pragma unroll
  for (int j = 0; j < 8; ++j) {
    hv.u[j] = sh[mb + j][ch];
    lv.u[j] = sl[mb + j][ch];
  }
  *(short8v*)(outb)       = hv.v;   // h = 0 (hi)
  *(short8v*)(outb + 512) = lv.v;   // h = 1 (lo)
}

// ---------------------------------------------------------------------------
// ka_partial = adj @ (k_hi + k_lo) via bf16 MFMA. No LDS, no barriers.
// Each wave: 16 output rows x 64 ch, streams adj (A) from HBM with explicit
// next-slab prefetch held in registers, B-frags from frag-linear kt (L1-hot:
// all 4 waves of a block read the same 8KB slab). adj in {0,1} exact in bf16.
// All 10 loads/slab live simultaneously -> ~VGPR 100, 4 waves/SIMD, and the
// loads actually overlap (r4 failure: VGPR=56 allocator serialized them).
// C/D: col = l&15, row = (l>>4)*4 + reg   [m89-verified, r3/r4-passing].
// ---------------------------------------------------------------------------
__global__ __launch_bounds__(256)
void adjk_mfma(const float* __restrict__ adj,
               const unsigned short* __restrict__ ktf,
               float* __restrict__ kapart) {
  const int lane = threadIdx.x & 63;
  const int wid  = threadIdx.x >> 6;
  const int g0   = blockIdx.x * 64 + wid * 16;  // global output row tile
  const int b    = g0 >> 12;                    // batch
  const int split = blockIdx.y;
  const int k0   = split * KCHUNK;
  const int slab0 = k0 >> 5;

  const int arow = lane & 15;
  const int koff = (lane >> 4) << 3;            // 0,8,16,24

  const float* aptr = adj + (size_t)(g0 + arow) * N_ + k0 + koff;
  const unsigned short* kbase =
      ktf + (size_t)(b * 128 + slab0) * 4096 + (size_t)lane * 8;

  f32x4 acc[4] = {{0.f,0.f,0.f,0.f},{0.f,0.f,0.f,0.f},
                  {0.f,0.f,0.f,0.f},{0.f,0.f,0.f,0.f}};

  // prefetch slab 0 A
  float4 a0 = *(const float4*)(aptr);
  float4 a1 = *(const float4*)(aptr + 4);

  for (int s = 0; s < 32; ++s) {
    // B-frags for slab s: 8 contiguous 16B/lane loads, all live at once
    const unsigned short* kb = kbase + (size_t)s * 4096;
    const short8v b00 = *(const short8v*)(kb);          // c=0 hi
    const short8v b01 = *(const short8v*)(kb + 512);    // c=0 lo
    const short8v b10 = *(const short8v*)(kb + 1024);
    const short8v b11 = *(const short8v*)(kb + 1536);
    const short8v b20 = *(const short8v*)(kb + 2048);
    const short8v b21 = *(const short8v*)(kb + 2560);
    const short8v b30 = *(const short8v*)(kb + 3072);
    const short8v b31 = *(const short8v*)(kb + 3584);

    // prefetch next slab A (clamped re-load of slab 31 on last iter)
    const int sn = (s < 31) ? s + 1 : 31;
    const float4 n0 = *(const float4*)(aptr + sn * 32);
    const float4 n1 = *(const float4*)(aptr + sn * 32 + 4);

    // convert current A to bf16 (exact for 0.0/1.0)
    union { short8v v; unsigned short u[8]; } af;
    const float av[8] = {a0.x, a0.y, a0.z, a0.w, a1.x, a1.y, a1.z, a1.w};
#pragma unroll
    for (int j = 0; j < 8; ++j)
      af.u[j] = (unsigned short)(__float_as_uint(av[j]) >> 16);

    acc[0] = __builtin_amdgcn_mfma_f32_16x16x32_bf16(af.v, b00, acc[0], 0, 0, 0);
    acc[0] = __builtin_amdgcn_mfma_f32_16x16x32_bf16(af.v, b01, acc[0], 0, 0, 0);
    acc[1] = __builtin_amdgcn_mfma_f32_16x16x32_bf16(af.v, b10, acc[1], 0, 0, 0);
    acc[1] = __builtin_amdgcn_mfma_f32_16x16x32_bf16(af.v, b11, acc[1], 0, 0, 0);
    acc[2] = __builtin_amdgcn_mfma_f32_16x16x32_bf16(af.v, b20, acc[2], 0, 0, 0);
    acc[2] = __builtin_amdgcn_mfma_f32_16x16x32_bf16(af.v, b21, acc[2], 0, 0, 0);
    acc[3] = __builtin_amdgcn_mfma_f32_16x16x32_bf16(af.v, b30, acc[3], 0, 0, 0);
    acc[3] = __builtin_amdgcn_mfma_f32_16x16x32_bf16(af.v, b31, acc[3], 0, 0, 0);

    a0 = n0; a1 = n1;
  }

  // write partials: kapart[split][g][ch]
  float* outp = kapart +
      ((size_t)split * (B_ * N_) + g0 + ((lane >> 4) << 2)) * ATT + (lane & 15);
#pragma unroll
  for (int c = 0; c < 4; ++c)
#pragma unroll
    for (int r = 0; r < 4; ++r)
      outp[(size_t)r * ATT + c * 16] = acc[c][r];
}

// ---------------------------------------------------------------------------
// wpre[row] = (1/8) * q[row] . (sum of KSPLIT ka partials)  — one wave/row
// ---------------------------------------------------------------------------
__global__ __launch_bounds__(256)
void qdot(const float* __restrict__ qk, const float* __restrict__ kapart,
          float* __restrict__ wpre) {
  const int wid  = threadIdx.x >> 6;
  const int lane = threadIdx.x & 63;
  const int row  = blockIdx.x * 4 + wid;   // b*N + n

  float ka = 0.f;
#pragma unroll
  for (int s = 0; s < KSPLIT; ++s)
    ka += kapart[((size_t)s * B_ * N_ + row) * ATT + lane];

  const float q = qk[(size_t)row * QKD + lane];
  float val = q * ka;
#pragma unroll
  for (int off = 32; off; off >>= 1) val += __shfl_xor(val, off);
  if (lane == 0) wpre[row] = val * 0.125f;   // 1/sqrt(64)
}

// ---------------------------------------------------------------------------
// Softmax over the bag dimension (N=4096) per batch, in-place.
// ---------------------------------------------------------------------------
__global__ __launch_bounds__(256)
void softmax_bag(float* __restrict__ w) {
  __shared__ float red[256];
  const int b = blockIdx.x;
  float* wb = w + (size_t)b * N_;
  const int t = threadIdx.x;

  float vals[16];
  float mx = -1e30f;
#pragma unroll
  for (int i = 0; i < 16; ++i) {
    vals[i] = wb[t + i * 256];
    mx = fmaxf(mx, vals[i]);
  }
  red[t] = mx; __syncthreads();
  for (int s = 128; s; s >>= 1) {
    if (t < s) red[t] = fmaxf(red[t], red[t + s]);
    __syncthreads();
  }
  mx = red[0];
  __syncthreads();

  float sum = 0.f;
#pragma unroll
  for (int i = 0; i < 16; ++i) {
    vals[i] = expf(vals[i] - mx);
    sum += vals[i];
  }
  red[t] = sum; __syncthreads();
  for (int s = 128; s; s >>= 1) {
    if (t < s) red[t] += red[t + s];
    __syncthreads();
  }
  const float inv = 1.f / red[0];
#pragma unroll
  for (int i = 0; i < 16; ++i) wb[t + i * 256] = vals[i] * inv;
}

// ---------------------------------------------------------------------------
// out[b,n,:] *= w[b,n]   (v was written directly into d_out)
// ---------------------------------------------------------------------------
__global__ __launch_bounds__(256)
void scale_v(float* __restrict__ out, const float* __restrict__ w, int total4) {
  int idx = blockIdx.x * blockDim.x + threadIdx.x;
  const int stride = gridDim.x * blockDim.x;
  for (; idx < total4; idx += stride) {
    float4 v = ((const float4*)out)[idx];
    const float s = w[idx >> 7];                  // 512/4 = 128 float4 per row
    v.x *= s; v.y *= s; v.z *= s; v.w *= s;
    ((float4*)out)[idx] = v;
  }
}

extern "C" void kernel_launch(void* const* d_in, const int* in_sizes, int n_in,
                              void* d_out, int out_size, void* d_ws, size_t ws_size,
                              hipStream_t stream) {
  const float* x    = (const float*)d_in[0];   // (B,N,512)
  const float* adj  = (const float*)d_in[1];   // (B,N,N)
  const float* W_qk = (const float*)d_in[2];   // (128,512)
  const float* W_v  = (const float*)d_in[3];   // (512,512)
  float* out = (float*)d_out;                  // (B,N,512)

  float* qk     = (float*)d_ws;                              // 8 MB
  float* kapart = qk + (size_t)B_ * N_ * QKD;                // 16 MB
  float* wpre   = kapart + (size_t)KSPLIT * B_ * N_ * ATT;   // 64 KB
  unsigned short* ktf = (unsigned short*)(wpre + B_ * N_);   // 4 MB frag-linear

  const int M = B_ * N_;  // 16384

  // v = x @ W_v^T  -> directly into d_out
  {
    dim3 grid(M / 64, IND / 64);
    gemm_nt_f32<<<grid, 256, 0, stream>>>(x, W_v, out, M, IND, IND);
  }
  // qk = x @ W_qk^T -> workspace
  {
    dim3 grid(M / 64, QKD / 64);
    gemm_nt_f32<<<grid, 256, 0, stream>>>(x, W_qk, qk, M, IND, QKD);
  }
  // k -> frag-linear bf16 hi/lo table
  prep_k<<<B_ * 128, 256, 0, stream>>>(qk, ktf);
  // ka partials = adj @ k via streaming bf16 MFMA
  {
    dim3 grid(M / 64, KSPLIT);
    adjk_mfma<<<grid, 256, 0, stream>>>(adj, ktf, kapart);
  }
  // wpre = q . ka / 8
  qdot<<<M / 4, 256, 0, stream>>>(qk, kapart, wpre);
  // softmax over bag dim
  softmax_bag<<<B_, 256, 0, stream>>>(wpre);
  // out *= w
  const int total4 = M * (IND / 4);
  scale_v<<<2048, 256, 0, stream>>>(out, wpre, total4);
}

// Round 6
// 518.943 us; speedup vs baseline: 1.2444x; 1.1635x over previous
//
#include <hip/hip_runtime.h>
#include <hip/hip_bf16.h>

// Problem constants
#define B_   4
#define N_   4096
#define IND  512
#define ATT  64
#define QKD  128   // 2*ATT

// adj@k split-K
#define KSPLIT 4
#define KCHUNK 1024   // 4096 / KSPLIT; 32 slabs of 32 k's each

typedef __attribute__((ext_vector_type(8))) short short8v;  // 8 bf16
typedef __attribute__((ext_vector_type(4))) float f32x4;

__device__ __forceinline__ void f8_to_bf16_hilo(const float4& v0, const float4& v1,
                                                short8v& hi, short8v& lo) {
  union { short8v v; unsigned short u[8]; } h, l;
  const float av[8] = {v0.x, v0.y, v0.z, v0.w, v1.x, v1.y, v1.z, v1.w};
#pragma unroll
  for (int j = 0; j < 8; ++j) {
    const unsigned short hu = (unsigned short)(__float_as_uint(av[j]) >> 16);
    const float fh = __uint_as_float((unsigned)hu << 16);
    h.u[j] = hu;
    l.u[j] = (unsigned short)(__float_as_uint(av[j] - fh) >> 16);
  }
  hi = h.v; lo = l.v;
}

// ---------------------------------------------------------------------------
// prep_frag: row-major f32 src[nrows][512] -> frag-linear bf16 hi/lo table:
//   dst[((ct*16 + slab)*2 + h)*512 + lane*8 + j]
//     = bf16_h( src[ct*16 + (lane&15)][slab*32 + (lane>>4)*8 + j] )
// This is exactly the A-frag AND B-frag lane mapping for mfma_f32_16x16x32_bf16
// (verified by r3-r5 passing adjk). One wave per 16-row tile (ct).
// ---------------------------------------------------------------------------
__global__ __launch_bounds__(256)
void prep_frag(const float* __restrict__ src, unsigned short* __restrict__ dst,
               int nct) {
  const int wid = threadIdx.x >> 6, lane = threadIdx.x & 63;
  const int ct = blockIdx.x * 4 + wid;
  if (ct >= nct) return;
  const float* s = src + ((size_t)ct * 16 + (lane & 15)) * IND + ((lane >> 4) << 3);
  unsigned short* d = dst + (size_t)ct * 16 * 2 * 512 + (size_t)lane * 8;
#pragma unroll 4
  for (int slab = 0; slab < 16; ++slab) {
    const float4 v0 = *(const float4*)(s + slab * 32);
    const float4 v1 = *(const float4*)(s + slab * 32 + 4);
    short8v hv, lv;
    f8_to_bf16_hilo(v0, v1, hv, lv);
    *(short8v*)(d + (size_t)slab * 2 * 512)       = hv;  // h=0
    *(short8v*)(d + (size_t)slab * 2 * 512 + 512) = lv;  // h=1
  }
}

// ---------------------------------------------------------------------------
// gemm_mfma: C[16384][Nout] = X @ W^T via bf16 hi/lo MFMA (3-term):
//   C = Xh Wh + Xl Wh + Xh Wl   (err ~2^-16)
// xf: frag-linear X table (mt = row/16), wf: frag-linear W table (ct = col/16).
// Wave: 16 rows x 128 cols (8 c-tiles); block: 4 waves = 64 rows.
// Grid: (16384/64, Nout/128). No LDS, register-prefetched A, L2-hot W.
// C/D layout: col = lane&15, row = (lane>>4)*4 + r  [r3-r5 verified].
// ---------------------------------------------------------------------------
__global__ __launch_bounds__(256, 2)
void gemm_mfma(const unsigned short* __restrict__ xf,
               const unsigned short* __restrict__ wf,
               float* __restrict__ C, int Nout) {
  const int lane = threadIdx.x & 63;
  const int wid  = threadIdx.x >> 6;
  const int g0   = blockIdx.x * 64 + wid * 16;
  const int mt   = g0 >> 4;
  const int ct0  = blockIdx.y * 8;

  const unsigned short* xb = xf + (size_t)mt * 16 * 2 * 512 + (size_t)lane * 8;
  const unsigned short* wb = wf + (size_t)ct0 * 16 * 2 * 512 + (size_t)lane * 8;

  f32x4 acc[8] = {{0.f,0.f,0.f,0.f},{0.f,0.f,0.f,0.f},{0.f,0.f,0.f,0.f},
                  {0.f,0.f,0.f,0.f},{0.f,0.f,0.f,0.f},{0.f,0.f,0.f,0.f},
                  {0.f,0.f,0.f,0.f},{0.f,0.f,0.f,0.f}};

  short8v axh = *(const short8v*)(xb);
  short8v axl = *(const short8v*)(xb + 512);

  for (int slab = 0; slab < 16; ++slab) {
    const int sn = (slab < 15) ? slab + 1 : 15;
    const short8v nxh = *(const short8v*)(xb + (size_t)sn * 1024);
    const short8v nxl = *(const short8v*)(xb + (size_t)sn * 1024 + 512);

#pragma unroll
    for (int c = 0; c < 8; ++c) {
      const unsigned short* wp = wb + ((size_t)(c * 16 + slab) * 2) * 512;
      const short8v bh = *(const short8v*)(wp);
      const short8v bl = *(const short8v*)(wp + 512);
      acc[c] = __builtin_amdgcn_mfma_f32_16x16x32_bf16(axh, bh, acc[c], 0, 0, 0);
      acc[c] = __builtin_amdgcn_mfma_f32_16x16x32_bf16(axl, bh, acc[c], 0, 0, 0);
      acc[c] = __builtin_amdgcn_mfma_f32_16x16x32_bf16(axh, bl, acc[c], 0, 0, 0);
    }
    axh = nxh; axl = nxl;
  }

  float* outp = C + ((size_t)g0 + ((lane >> 4) << 2)) * Nout + ct0 * 16 + (lane & 15);
#pragma unroll
  for (int c = 0; c < 8; ++c)
#pragma unroll
    for (int r = 0; r < 4; ++r)
      outp[(size_t)r * Nout + c * 16] = acc[c][r];
}

// ---------------------------------------------------------------------------
// prep_k: k part of qk (f32) -> frag-linear bf16 hi/lo table for adjk:
//   ktf[((((b*128 + slab)*4 + c)*2 + h)*64 + lane)*8 + j]   [r5-verified]
// ---------------------------------------------------------------------------
__global__ __launch_bounds__(256)
void prep_k(const float* __restrict__ qk, unsigned short* __restrict__ ktf) {
  __shared__ unsigned short sh[32][68];
  __shared__ unsigned short sl[32][68];
  const int b    = blockIdx.x >> 7;
  const int slab = blockIdx.x & 127;
  const int t = threadIdx.x;

#pragma unroll
  for (int i = 0; i < 2; ++i) {
    const int f = t + i * 256;          // 0..511 float4s
    const int ml  = f >> 4;             // 0..31
    const int ch4 = (f & 15) << 2;      // 0..60
    const float4 v = *(const float4*)(qk +
        ((size_t)b * N_ + slab * 32 + ml) * QKD + ATT + ch4);
    const float vv[4] = {v.x, v.y, v.z, v.w};
#pragma unroll
    for (int j = 0; j < 4; ++j) {
      const unsigned short hi = (unsigned short)(__float_as_uint(vv[j]) >> 16);
      const float fhi = __uint_as_float((unsigned)hi << 16);
      const unsigned short lo = (unsigned short)(__float_as_uint(vv[j] - fhi) >> 16);
      sh[ml][ch4 + j] = hi;
      sl[ml][ch4 + j] = lo;
    }
  }
  __syncthreads();

  const int lane = t & 63;
  const int c    = t >> 6;              // 0..3
  const int mb   = (lane >> 4) << 3;    // m base: 0,8,16,24
  const int ch   = c * 16 + (lane & 15);
  unsigned short* outb = ktf +
      (((size_t)(b * 128 + slab) * 4 + c) * 2) * 512 + (size_t)lane * 8;
  union { short8v v; unsigned short u[8]; } hv, lv;
#pragma unroll
  for (int j = 0; j < 8; ++j) {
    hv.u[j] = sh[mb + j][ch];
    lv.u[j] = sl[mb + j][ch];
  }
  *(short8v*)(outb)       = hv.v;   // h = 0 (hi)
  *(short8v*)(outb + 512) = lv.v;   // h = 1 (lo)
}

// ---------------------------------------------------------------------------
// ka_partial = adj @ (k_hi + k_lo) via bf16 MFMA. No LDS, no barriers.
// Wave: 32 output rows (2 row-tiles) x 64 ch -> B-frag traffic halves per
// output vs r5. __launch_bounds__(256,2) gives the allocator 256 VGPR so all
// 12 loads/slab stay live concurrently (r4/r5 failure: VGPR=56 serialized).
// Grid (128, KSPLIT): 512 blocks, 8 waves/CU; per-CU slab-round is BW-bound
// (96 VMEM x 16cy = 1536cy < 3200cy HBM floor).
// ---------------------------------------------------------------------------
__global__ __launch_bounds__(256, 2)
void adjk_mfma(const float* __restrict__ adj,
               const unsigned short* __restrict__ ktf,
               float* __restrict__ kapart) {
  const int lane = threadIdx.x & 63;
  const int wid  = threadIdx.x >> 6;
  const int g0   = blockIdx.x * 128 + wid * 32;  // 2 row-tiles: g0, g0+16
  const int b    = g0 >> 12;
  const int split = blockIdx.y;
  const int k0   = split * KCHUNK;
  const int slab0 = k0 >> 5;

  const int arow = lane & 15;
  const int koff = (lane >> 4) << 3;

  const float* aptr0 = adj + (size_t)(g0 + arow) * N_ + k0 + koff;
  const float* aptr1 = aptr0 + (size_t)16 * N_;
  const unsigned short* kbase =
      ktf + (size_t)(b * 128 + slab0) * 4096 + (size_t)lane * 8;

  f32x4 acc[2][4] = {{{0.f,0.f,0.f,0.f},{0.f,0.f,0.f,0.f},
                      {0.f,0.f,0.f,0.f},{0.f,0.f,0.f,0.f}},
                     {{0.f,0.f,0.f,0.f},{0.f,0.f,0.f,0.f},
                      {0.f,0.f,0.f,0.f},{0.f,0.f,0.f,0.f}}};

  float4 a00 = *(const float4*)(aptr0);
  float4 a01 = *(const float4*)(aptr0 + 4);
  float4 a10 = *(const float4*)(aptr1);
  float4 a11 = *(const float4*)(aptr1 + 4);

  for (int s = 0; s < 32; ++s) {
    const unsigned short* kb = kbase + (size_t)s * 4096;
    const short8v b00 = *(const short8v*)(kb);          // c=0 hi
    const short8v b01 = *(const short8v*)(kb + 512);    // c=0 lo
    const short8v b10 = *(const short8v*)(kb + 1024);
    const short8v b11 = *(const short8v*)(kb + 1536);
    const short8v b20 = *(const short8v*)(kb + 2048);
    const short8v b21 = *(const short8v*)(kb + 2560);
    const short8v b30 = *(const short8v*)(kb + 3072);
    const short8v b31 = *(const short8v*)(kb + 3584);

    const int sn = (s < 31) ? s + 1 : 31;
    const float4 n00 = *(const float4*)(aptr0 + sn * 32);
    const float4 n01 = *(const float4*)(aptr0 + sn * 32 + 4);
    const float4 n10 = *(const float4*)(aptr1 + sn * 32);
    const float4 n11 = *(const float4*)(aptr1 + sn * 32 + 4);

    // A -> bf16 (exact for 0.0/1.0)
    union { short8v v; unsigned short u[8]; } af0, af1;
    {
      const float av0[8] = {a00.x,a00.y,a00.z,a00.w,a01.x,a01.y,a01.z,a01.w};
      const float av1[8] = {a10.x,a10.y,a10.z,a10.w,a11.x,a11.y,a11.z,a11.w};
#pragma unroll
      for (int j = 0; j < 8; ++j) {
        af0.u[j] = (unsigned short)(__float_as_uint(av0[j]) >> 16);
        af1.u[j] = (unsigned short)(__float_as_uint(av1[j]) >> 16);
      }
    }

    acc[0][0] = __builtin_amdgcn_mfma_f32_16x16x32_bf16(af0.v, b00, acc[0][0], 0,0,0);
    acc[0][0] = __builtin_amdgcn_mfma_f32_16x16x32_bf16(af0.v, b01, acc[0][0], 0,0,0);
    acc[0][1] = __builtin_amdgcn_mfma_f32_16x16x32_bf16(af0.v, b10, acc[0][1], 0,0,0);
    acc[0][1] = __builtin_amdgcn_mfma_f32_16x16x32_bf16(af0.v, b11, acc[0][1], 0,0,0);
    acc[0][2] = __builtin_amdgcn_mfma_f32_16x16x32_bf16(af0.v, b20, acc[0][2], 0,0,0);
    acc[0][2] = __builtin_amdgcn_mfma_f32_16x16x32_bf16(af0.v, b21, acc[0][2], 0,0,0);
    acc[0][3] = __builtin_amdgcn_mfma_f32_16x16x32_bf16(af0.v, b30, acc[0][3], 0,0,0);
    acc[0][3] = __builtin_amdgcn_mfma_f32_16x16x32_bf16(af0.v, b31, acc[0][3], 0,0,0);
    acc[1][0] = __builtin_amdgcn_mfma_f32_16x16x32_bf16(af1.v, b00, acc[1][0], 0,0,0);
    acc[1][0] = __builtin_amdgcn_mfma_f32_16x16x32_bf16(af1.v, b01, acc[1][0], 0,0,0);
    acc[1][1] = __builtin_amdgcn_mfma_f32_16x16x32_bf16(af1.v, b10, acc[1][1], 0,0,0);
    acc[1][1] = __builtin_amdgcn_mfma_f32_16x16x32_bf16(af1.v, b11, acc[1][1], 0,0,0);
    acc[1][2] = __builtin_amdgcn_mfma_f32_16x16x32_bf16(af1.v, b20, acc[1][2], 0,0,0);
    acc[1][2] = __builtin_amdgcn_mfma_f32_16x16x32_bf16(af1.v, b21, acc[1][2], 0,0,0);
    acc[1][3] = __builtin_amdgcn_mfma_f32_16x16x32_bf16(af1.v, b30, acc[1][3], 0,0,0);
    acc[1][3] = __builtin_amdgcn_mfma_f32_16x16x32_bf16(af1.v, b31, acc[1][3], 0,0,0);

    a00 = n00; a01 = n01; a10 = n10; a11 = n11;
  }

  // write partials: kapart[split][g][ch], two 16-row tiles
#pragma unroll
  for (int tile = 0; tile < 2; ++tile) {
    float* outp = kapart +
        ((size_t)split * (B_ * N_) + g0 + tile * 16 + ((lane >> 4) << 2)) * ATT
        + (lane & 15);
#pragma unroll
    for (int c = 0; c < 4; ++c)
#pragma unroll
      for (int r = 0; r < 4; ++r)
        outp[(size_t)r * ATT + c * 16] = acc[tile][c][r];
  }
}

// ---------------------------------------------------------------------------
// wpre[row] = (1/8) * q[row] . (sum of KSPLIT ka partials)  — one wave/row
// ---------------------------------------------------------------------------
__global__ __launch_bounds__(256)
void qdot(const float* __restrict__ qk, const float* __restrict__ kapart,
          float* __restrict__ wpre) {
  const int wid  = threadIdx.x >> 6;
  const int lane = threadIdx.x & 63;
  const int row  = blockIdx.x * 4 + wid;   // b*N + n

  float ka = 0.f;
#pragma unroll
  for (int s = 0; s < KSPLIT; ++s)
    ka += kapart[((size_t)s * B_ * N_ + row) * ATT + lane];

  const float q = qk[(size_t)row * QKD + lane];
  float val = q * ka;
#pragma unroll
  for (int off = 32; off; off >>= 1) val += __shfl_xor(val, off);
  if (lane == 0) wpre[row] = val * 0.125f;   // 1/sqrt(64)
}

// ---------------------------------------------------------------------------
// Softmax over the bag dimension (N=4096) per batch, in-place.
// ---------------------------------------------------------------------------
__global__ __launch_bounds__(256)
void softmax_bag(float* __restrict__ w) {
  __shared__ float red[256];
  const int b = blockIdx.x;
  float* wb = w + (size_t)b * N_;
  const int t = threadIdx.x;

  float vals[16];
  float mx = -1e30f;
#pragma unroll
  for (int i = 0; i < 16; ++i) {
    vals[i] = wb[t + i * 256];
    mx = fmaxf(mx, vals[i]);
  }
  red[t] = mx; __syncthreads();
  for (int s = 128; s; s >>= 1) {
    if (t < s) red[t] = fmaxf(red[t], red[t + s]);
    __syncthreads();
  }
  mx = red[0];
  __syncthreads();

  float sum = 0.f;
#pragma unroll
  for (int i = 0; i < 16; ++i) {
    vals[i] = expf(vals[i] - mx);
    sum += vals[i];
  }
  red[t] = sum; __syncthreads();
  for (int s = 128; s; s >>= 1) {
    if (t < s) red[t] += red[t + s];
    __syncthreads();
  }
  const float inv = 1.f / red[0];
#pragma unroll
  for (int i = 0; i < 16; ++i) wb[t + i * 256] = vals[i] * inv;
}

// ---------------------------------------------------------------------------
// out[b,n,:] *= w[b,n]   (v was written directly into d_out)
// ---------------------------------------------------------------------------
__global__ __launch_bounds__(256)
void scale_v(float* __restrict__ out, const float* __restrict__ w, int total4) {
  int idx = blockIdx.x * blockDim.x + threadIdx.x;
  const int stride = gridDim.x * blockDim.x;
  for (; idx < total4; idx += stride) {
    float4 v = ((const float4*)out)[idx];
    const float s = w[idx >> 7];                  // 512/4 = 128 float4 per row
    v.x *= s; v.y *= s; v.z *= s; v.w *= s;
    ((float4*)out)[idx] = v;
  }
}

extern "C" void kernel_launch(void* const* d_in, const int* in_sizes, int n_in,
                              void* d_out, int out_size, void* d_ws, size_t ws_size,
                              hipStream_t stream) {
  const float* x    = (const float*)d_in[0];   // (B,N,512)
  const float* adj  = (const float*)d_in[1];   // (B,N,N)
  const float* W_qk = (const float*)d_in[2];   // (128,512)
  const float* W_v  = (const float*)d_in[3];   // (512,512)
  float* out = (float*)d_out;                  // (B,N,512)

  float* qk     = (float*)d_ws;                              // 8 MB
  float* kapart = qk + (size_t)B_ * N_ * QKD;                // 16 MB
  float* wpre   = kapart + (size_t)KSPLIT * B_ * N_ * ATT;   // 64 KB
  unsigned short* ktf  = (unsigned short*)(wpre + B_ * N_);  // 4 MB frag-linear k
  unsigned short* xft  = ktf + (size_t)B_ * 128 * 4096;      // 32 MB frag-linear x
  unsigned short* wvf  = xft + (size_t)1024 * 16 * 2 * 512;  // 1 MB frag-linear W_v
  unsigned short* wqkf = wvf + (size_t)32 * 16 * 2 * 512;    // 256 KB frag W_qk

  const int M = B_ * N_;  // 16384

  // frag-linear bf16 hi/lo tables for X, W_v, W_qk
  prep_frag<<<256, 256, 0, stream>>>(x, xft, 1024);
  prep_frag<<<8, 256, 0, stream>>>(W_v, wvf, 32);
  prep_frag<<<2, 256, 0, stream>>>(W_qk, wqkf, 8);

  // qk = x @ W_qk^T (MFMA 3-term hi/lo)
  {
    dim3 grid(M / 64, QKD / 128);
    gemm_mfma<<<grid, 256, 0, stream>>>(xft, wqkf, qk, QKD);
  }
  // v = x @ W_v^T -> directly into d_out
  {
    dim3 grid(M / 64, IND / 128);
    gemm_mfma<<<grid, 256, 0, stream>>>(xft, wvf, out, IND);
  }
  // k -> frag-linear bf16 hi/lo table
  prep_k<<<B_ * 128, 256, 0, stream>>>(qk, ktf);
  // ka partials = adj @ k via streaming bf16 MFMA
  {
    dim3 grid(M / 128, KSPLIT);
    adjk_mfma<<<grid, 256, 0, stream>>>(adj, ktf, kapart);
  }
  // wpre = q . ka / 8
  qdot<<<M / 4, 256, 0, stream>>>(qk, kapart, wpre);
  // softmax over bag dim
  softmax_bag<<<B_, 256, 0, stream>>>(wpre);
  // out *= w
  const int total4 = M * (IND / 4);
  scale_v<<<2048, 256, 0, stream>>>(out, wpre, total4);
}

// Round 8
// 514.581 us; speedup vs baseline: 1.2549x; 1.0085x over previous
//
#include <hip/hip_runtime.h>
#include <hip/hip_bf16.h>

// Problem constants
#define B_   4
#define N_   4096
#define IND  512
#define ATT  64
#define QKD  128   // 2*ATT

// adj@k split-K (m97-style LDS version)
#define KSPLIT 2
#define KCHUNK 2048   // 4096 / KSPLIT
#define AK_NT  32     // K-tiles of 64 per block

typedef __attribute__((ext_vector_type(8))) short short8v;  // 8 bf16
typedef __attribute__((ext_vector_type(4))) float f32x4;

__device__ __forceinline__ void gload_lds16(const void* g, void* l) {
  __builtin_amdgcn_global_load_lds(
      (const __attribute__((address_space(1))) unsigned int*)g,
      (__attribute__((address_space(3))) unsigned int*)l, 16, 0, 0);
}

__device__ __forceinline__ void f8_to_bf16_hilo(const float4& v0, const float4& v1,
                                                short8v& hi, short8v& lo) {
  union { short8v v; unsigned short u[8]; } h, l;
  const float av[8] = {v0.x, v0.y, v0.z, v0.w, v1.x, v1.y, v1.z, v1.w};
#pragma unroll
  for (int j = 0; j < 8; ++j) {
    const unsigned short hu = (unsigned short)(__float_as_uint(av[j]) >> 16);
    const float fh = __uint_as_float((unsigned)hu << 16);
    h.u[j] = hu;
    l.u[j] = (unsigned short)(__float_as_uint(av[j] - fh) >> 16);
  }
  hi = h.v; lo = l.v;
}

// ---------------------------------------------------------------------------
// prep_frag: row-major f32 src[nrows][512] -> frag-linear bf16 hi/lo table:
//   dst[((ct*16 + slab)*2 + h)*512 + lane*8 + j]
//     = bf16_h( src[ct*16 + (lane&15)][slab*32 + (lane>>4)*8 + j] )
// (A-frag AND B-frag lane mapping for mfma_f32_16x16x32_bf16; r3-r6 verified.)
// ---------------------------------------------------------------------------
__global__ __launch_bounds__(256)
void prep_frag(const float* __restrict__ src, unsigned short* __restrict__ dst,
               int nct) {
  const int wid = threadIdx.x >> 6, lane = threadIdx.x & 63;
  const int ct = blockIdx.x * 4 + wid;
  if (ct >= nct) return;
  const float* s = src + ((size_t)ct * 16 + (lane & 15)) * IND + ((lane >> 4) << 3);
  unsigned short* d = dst + (size_t)ct * 16 * 2 * 512 + (size_t)lane * 8;
#pragma unroll 4
  for (int slab = 0; slab < 16; ++slab) {
    const float4 v0 = *(const float4*)(s + slab * 32);
    const float4 v1 = *(const float4*)(s + slab * 32 + 4);
    short8v hv, lv;
    f8_to_bf16_hilo(v0, v1, hv, lv);
    *(short8v*)(d + (size_t)slab * 2 * 512)       = hv;
    *(short8v*)(d + (size_t)slab * 2 * 512 + 512) = lv;
  }
}

// ---------------------------------------------------------------------------
// gemm_mfma: C = X @ W^T via bf16 hi/lo MFMA, 3-term (err ~2^-16).
// Optional fused row-scale epilogue (wsc != nullptr): C[row][:] *= wsc[row].
// Wave: 16 rows x 128 cols; block 64 rows; grid (M/64, Nout/128). [r6-passing]
// ---------------------------------------------------------------------------
__global__ __launch_bounds__(256, 2)
void gemm_mfma(const unsigned short* __restrict__ xf,
               const unsigned short* __restrict__ wf,
               float* __restrict__ C, int Nout,
               const float* __restrict__ wsc) {
  const int lane = threadIdx.x & 63;
  const int wid  = threadIdx.x >> 6;
  const int g0   = blockIdx.x * 64 + wid * 16;
  const int mt   = g0 >> 4;
  const int ct0  = blockIdx.y * 8;

  const unsigned short* xb = xf + (size_t)mt * 16 * 2 * 512 + (size_t)lane * 8;
  const unsigned short* wb = wf + (size_t)ct0 * 16 * 2 * 512 + (size_t)lane * 8;

  f32x4 acc[8] = {{0.f,0.f,0.f,0.f},{0.f,0.f,0.f,0.f},{0.f,0.f,0.f,0.f},
                  {0.f,0.f,0.f,0.f},{0.f,0.f,0.f,0.f},{0.f,0.f,0.f,0.f},
                  {0.f,0.f,0.f,0.f},{0.f,0.f,0.f,0.f}};

  short8v axh = *(const short8v*)(xb);
  short8v axl = *(const short8v*)(xb + 512);

  for (int slab = 0; slab < 16; ++slab) {
    const int sn = (slab < 15) ? slab + 1 : 15;
    const short8v nxh = *(const short8v*)(xb + (size_t)sn * 1024);
    const short8v nxl = *(const short8v*)(xb + (size_t)sn * 1024 + 512);

#pragma unroll
    for (int c = 0; c < 8; ++c) {
      const unsigned short* wp = wb + ((size_t)(c * 16 + slab) * 2) * 512;
      const short8v bh = *(const short8v*)(wp);
      const short8v bl = *(const short8v*)(wp + 512);
      acc[c] = __builtin_amdgcn_mfma_f32_16x16x32_bf16(axh, bh, acc[c], 0, 0, 0);
      acc[c] = __builtin_amdgcn_mfma_f32_16x16x32_bf16(axl, bh, acc[c], 0, 0, 0);
      acc[c] = __builtin_amdgcn_mfma_f32_16x16x32_bf16(axh, bl, acc[c], 0, 0, 0);
    }
    axh = nxh; axl = nxl;
  }

  float* outp = C + ((size_t)g0 + ((lane >> 4) << 2)) * Nout + ct0 * 16 + (lane & 15);
#pragma unroll
  for (int r = 0; r < 4; ++r) {
    const float s = wsc ? wsc[g0 + ((lane >> 4) << 2) + r] : 1.0f;
#pragma unroll
    for (int c = 0; c < 8; ++c)
      outp[(size_t)r * Nout + c * 16] = acc[c][r] * s;
  }
}

// ---------------------------------------------------------------------------
// prep_k: k part of qk (f32) -> frag-linear bf16 hi/lo table:
//   ktf[((((b*128 + slab)*4 + c)*2 + h)*64 + lane)*8 + j]   [r5/r6-verified]
// ---------------------------------------------------------------------------
__global__ __launch_bounds__(256)
void prep_k(const float* __restrict__ qk, unsigned short* __restrict__ ktf) {
  __shared__ unsigned short sh[32][68];
  __shared__ unsigned short sl[32][68];
  const int b    = blockIdx.x >> 7;
  const int slab = blockIdx.x & 127;
  const int t = threadIdx.x;

#pragma unroll
  for (int i = 0; i < 2; ++i) {
    const int f = t + i * 256;
    const int ml  = f >> 4;
    const int ch4 = (f & 15) << 2;
    const float4 v = *(const float4*)(qk +
        ((size_t)b * N_ + slab * 32 + ml) * QKD + ATT + ch4);
    const float vv[4] = {v.x, v.y, v.z, v.w};
#pragma unroll
    for (int j = 0; j < 4; ++j) {
      const unsigned short hi = (unsigned short)(__float_as_uint(vv[j]) >> 16);
      const float fhi = __uint_as_float((unsigned)hi << 16);
      const unsigned short lo = (unsigned short)(__float_as_uint(vv[j] - fhi) >> 16);
      sh[ml][ch4 + j] = hi;
      sl[ml][ch4 + j] = lo;
    }
  }
  __syncthreads();

  const int lane = t & 63;
  const int c    = t >> 6;
  const int mb   = (lane >> 4) << 3;
  const int ch   = c * 16 + (lane & 15);
  unsigned short* outb = ktf +
      (((size_t)(b * 128 + slab) * 4 + c) * 2) * 512 + (size_t)lane * 8;
  union { short8v v; unsigned short u[8]; } hv, lv;
#pragma unroll
  for (int j = 0; j < 8; ++j) {
    hv.u[j] = sh[mb + j][ch];
    lv.u[j] = sl[mb + j][ch];
  }
  *(short8v*)(outb)       = hv.v;
  *(short8v*)(outb + 512) = lv.v;
}

// ---------------------------------------------------------------------------
// adjk_lds: ka_partial = adj @ (k_hi + k_lo), m97-style structure.
// Block: 128 rows x KCHUNK=2048 k, 4 waves (32 rows each). Grid (128,2) = 256
// blocks = 1/CU (LDS 96KB caps). Per K-tile (64 k): stage A (32KB f32) + B
// (16KB frag-linear bf16) into double-buffered LDS via global_load_lds DMA
// (no VGPR destinations -> compiler CANNOT serialize: r4-r6 failure mode),
// 2-barrier loop, depth-1 prefetch covers the BW window (874TF precedent).
// A bank conflicts (row-major [128][64] f32 = 16-way) fixed by chunk-XOR
// swizzle applied to the per-lane GLOBAL source addr + the ds_read addr
// (both-sides rule): slot(r,c) holds global chunk c^(r&7) -> 2-way = free.
// ---------------------------------------------------------------------------
__global__ __launch_bounds__(256)
void adjk_lds(const float* __restrict__ adj,
              const unsigned short* __restrict__ ktf,
              float* __restrict__ kapart) {
  __shared__ __align__(16) unsigned char smem[98304];
  // A: 2 x 32KB at 0, 32768; B: 2 x 16KB at 65536, 81920
  const int lane = threadIdx.x & 63;
  const int wid  = threadIdx.x >> 6;
  const int g0   = blockIdx.x * 128;
  const int b    = g0 >> 12;
  const int split = blockIdx.y;
  const int k0   = split * KCHUNK;

  const int lr   = lane >> 4;        // 0..3
  const int cch  = lane & 15;        // A-stage chunk / frag col

  auto STAGE = [&](int t, int buf) {
    const int kt = k0 + t * 64;
    // A: 8 x 1KB DMA per wave; rows wid*32 + i*4 + lr, source chunk XOR'd
    {
      const int rbase = wid * 32;
#pragma unroll
      for (int i = 0; i < 8; ++i) {
        const int r = rbase + i * 4 + lr;
        const int csrc = cch ^ (r & 7);
        const float* src = adj + (size_t)(g0 + r) * N_ + kt + csrc * 4;
        void* dst = smem + buf * 32768 + (rbase + i * 4) * 256;
        gload_lds16(src, dst);
      }
    }
    // B: 4 x 1KB DMA per wave; ktf slabs kt/32, kt/32+1 are 8192 contiguous shorts
    {
      const unsigned short* kb = ktf + ((size_t)b * 128 + (kt >> 5)) * 4096;
#pragma unroll
      for (int j = 0; j < 4; ++j) {
        const unsigned short* src = kb + (wid * 4 + j) * 512 + lane * 8;
        void* dst = smem + 65536 + buf * 16384 + (wid * 4 + j) * 1024;
        gload_lds16(src, dst);
      }
    }
  };

  f32x4 acc[2][4] = {{{0.f,0.f,0.f,0.f},{0.f,0.f,0.f,0.f},
                      {0.f,0.f,0.f,0.f},{0.f,0.f,0.f,0.f}},
                     {{0.f,0.f,0.f,0.f},{0.f,0.f,0.f,0.f},
                      {0.f,0.f,0.f,0.f},{0.f,0.f,0.f,0.f}}};

  STAGE(0, 0);
  __syncthreads();

  for (int t = 0; t < AK_NT; ++t) {
    const int cur = t & 1;
    if (t + 1 < AK_NT) STAGE(t + 1, cur ^ 1);

    const float* A = (const float*)(smem + cur * 32768);
    const unsigned short* Bp = (const unsigned short*)(smem + 65536 + cur * 16384);

#pragma unroll
    for (int s2 = 0; s2 < 2; ++s2) {
      const unsigned short* bb = Bp + s2 * 4096 + lane * 8;
      const short8v b0h = *(const short8v*)(bb);
      const short8v b0l = *(const short8v*)(bb + 512);
      const short8v b1h = *(const short8v*)(bb + 1024);
      const short8v b1l = *(const short8v*)(bb + 1536);
      const short8v b2h = *(const short8v*)(bb + 2048);
      const short8v b2l = *(const short8v*)(bb + 2560);
      const short8v b3h = *(const short8v*)(bb + 3072);
      const short8v b3l = *(const short8v*)(bb + 3584);

#pragma unroll
      for (int rt = 0; rt < 2; ++rt) {
        const int r = wid * 32 + rt * 16 + cch;
        const int cb = s2 * 8 + (lr << 1);
        const f32x4 a0 = *(const f32x4*)(A + r * 64 + ((cb ^ (r & 7)) << 2));
        const f32x4 a1 = *(const f32x4*)(A + r * 64 + (((cb + 1) ^ (r & 7)) << 2));
        union { short8v v; unsigned short u[8]; } af;
#pragma unroll
        for (int j = 0; j < 4; ++j) {
          af.u[j]     = (unsigned short)(__float_as_uint(a0[j]) >> 16);
          af.u[4 + j] = (unsigned short)(__float_as_uint(a1[j]) >> 16);
        }
        acc[rt][0] = __builtin_amdgcn_mfma_f32_16x16x32_bf16(af.v, b0h, acc[rt][0], 0,0,0);
        acc[rt][0] = __builtin_amdgcn_mfma_f32_16x16x32_bf16(af.v, b0l, acc[rt][0], 0,0,0);
        acc[rt][1] = __builtin_amdgcn_mfma_f32_16x16x32_bf16(af.v, b1h, acc[rt][1], 0,0,0);
        acc[rt][1] = __builtin_amdgcn_mfma_f32_16x16x32_bf16(af.v, b1l, acc[rt][1], 0,0,0);
        acc[rt][2] = __builtin_amdgcn_mfma_f32_16x16x32_bf16(af.v, b2h, acc[rt][2], 0,0,0);
        acc[rt][2] = __builtin_amdgcn_mfma_f32_16x16x32_bf16(af.v, b2l, acc[rt][2], 0,0,0);
        acc[rt][3] = __builtin_amdgcn_mfma_f32_16x16x32_bf16(af.v, b3h, acc[rt][3], 0,0,0);
        acc[rt][3] = __builtin_amdgcn_mfma_f32_16x16x32_bf16(af.v, b3l, acc[rt][3], 0,0,0);
      }
    }
    __syncthreads();
  }

  // write partials: kapart[split][row][ch]; C/D: col=lane&15, row=(lane>>4)*4+r
#pragma unroll
  for (int rt = 0; rt < 2; ++rt) {
    float* outp = kapart +
        ((size_t)split * (B_ * N_) + g0 + wid * 32 + rt * 16 + (lr << 2)) * ATT + cch;
#pragma unroll
    for (int c = 0; c < 4; ++c)
#pragma unroll
      for (int r = 0; r < 4; ++r)
        outp[(size_t)r * ATT + c * 16] = acc[rt][c][r];
  }
}

// ---------------------------------------------------------------------------
// wpre[row] = (1/8) * q[row] . (sum of KSPLIT ka partials)  — one wave/row
// ---------------------------------------------------------------------------
__global__ __launch_bounds__(256)
void qdot(const float* __restrict__ qk, const float* __restrict__ kapart,
          float* __restrict__ wpre) {
  const int wid  = threadIdx.x >> 6;
  const int lane = threadIdx.x & 63;
  const int row  = blockIdx.x * 4 + wid;

  float ka = 0.f;
#pragma unroll
  for (int s = 0; s < KSPLIT; ++s)
    ka += kapart[((size_t)s * B_ * N_ + row) * ATT + lane];

  const float q = qk[(size_t)row * QKD + lane];
  float val = q * ka;
#pragma unroll
  for (int off = 32; off; off >>= 1) val += __shfl_xor(val, off);
  if (lane == 0) wpre[row] = val * 0.125f;
}

// ---------------------------------------------------------------------------
// Softmax over the bag dimension (N=4096) per batch, in-place.
// ---------------------------------------------------------------------------
__global__ __launch_bounds__(256)
void softmax_bag(float* __restrict__ w) {
  __shared__ float red[256];
  const int b = blockIdx.x;
  float* wb = w + (size_t)b * N_;
  const int t = threadIdx.x;

  float vals[16];
  float mx = -1e30f;
#pragma unroll
  for (int i = 0; i < 16; ++i) {
    vals[i] = wb[t + i * 256];
    mx = fmaxf(mx, vals[i]);
  }
  red[t] = mx; __syncthreads();
  for (int s = 128; s; s >>= 1) {
    if (t < s) red[t] = fmaxf(red[t], red[t + s]);
    __syncthreads();
  }
  mx = red[0];
  __syncthreads();

  float sum = 0.f;
#pragma unroll
  for (int i = 0; i < 16; ++i) {
    vals[i] = expf(vals[i] - mx);
    sum += vals[i];
  }
  red[t] = sum; __syncthreads();
  for (int s = 128; s; s >>= 1) {
    if (t < s) red[t] += red[t + s];
    __syncthreads();
  }
  const float inv = 1.f / red[0];
#pragma unroll
  for (int i = 0; i < 16; ++i) wb[t + i * 256] = vals[i] * inv;
}

extern "C" void kernel_launch(void* const* d_in, const int* in_sizes, int n_in,
                              void* d_out, int out_size, void* d_ws, size_t ws_size,
                              hipStream_t stream) {
  const float* x    = (const float*)d_in[0];   // (B,N,512)
  const float* adj  = (const float*)d_in[1];   // (B,N,N)
  const float* W_qk = (const float*)d_in[2];   // (128,512)
  const float* W_v  = (const float*)d_in[3];   // (512,512)
  float* out = (float*)d_out;                  // (B,N,512)

  float* qk     = (float*)d_ws;                              // 8 MB
  float* kapart = qk + (size_t)B_ * N_ * QKD;                // 8 MB (KSPLIT=2)
  float* wpre   = kapart + (size_t)KSPLIT * B_ * N_ * ATT;   // 64 KB
  unsigned short* ktf  = (unsigned short*)(wpre + B_ * N_);  // 4 MB frag-linear k
  unsigned short* xft  = ktf + (size_t)B_ * 128 * 4096;      // 32 MB frag-linear x
  unsigned short* wvf  = xft + (size_t)1024 * 16 * 2 * 512;  // 1 MB frag W_v
  unsigned short* wqkf = wvf + (size_t)32 * 16 * 2 * 512;    // 256 KB frag W_qk

  const int M = B_ * N_;  // 16384

  // frag-linear bf16 hi/lo tables for X, W_v, W_qk
  prep_frag<<<256, 256, 0, stream>>>(x, xft, 1024);
  prep_frag<<<8, 256, 0, stream>>>(W_v, wvf, 32);
  prep_frag<<<2, 256, 0, stream>>>(W_qk, wqkf, 8);

  // qk = x @ W_qk^T
  {
    dim3 grid(M / 64, QKD / 128);
    gemm_mfma<<<grid, 256, 0, stream>>>(xft, wqkf, qk, QKD, nullptr);
  }
  // k -> frag-linear bf16 hi/lo table
  prep_k<<<B_ * 128, 256, 0, stream>>>(qk, ktf);
  // ka partials = adj @ k (m97-style LDS DMA GEMM)
  {
    dim3 grid(M / 128, KSPLIT);
    adjk_lds<<<grid, 256, 0, stream>>>(adj, ktf, kapart);
  }
  // wpre = q . ka / 8
  qdot<<<M / 4, 256, 0, stream>>>(qk, kapart, wpre);
  // softmax over bag dim
  softmax_bag<<<B_, 256, 0, stream>>>(wpre);
  // out = (x @ W_v^T) * w   (scale fused into epilogue; scale_v deleted)
  {
    dim3 grid(M / 64, IND / 128);
    gemm_mfma<<<grid, 256, 0, stream>>>(xft, wvf, out, IND, wpre);
  }
}